// Round 1
// baseline (635.930 us; speedup 1.0000x reference)
//
#include <hip/hip_runtime.h>

// ---------------- problem constants ----------------
#define DM    1024      // D_MODEL
#define DS    16        // D_STATE
#define DI    2048      // D_INNER
#define LSEQ  2048      // SEQ
#define BL    4096      // BATCH * SEQ rows

typedef float        f32x4 __attribute__((ext_vector_type(4)));
typedef unsigned int u32x4 __attribute__((ext_vector_type(4)));

__device__ __forceinline__ unsigned short f2bf(float f) {
    unsigned int u = __float_as_uint(f);
    u += 0x7fffu + ((u >> 16) & 1u);      // round-to-nearest-even
    return (unsigned short)(u >> 16);
}

__device__ __forceinline__ float silu_f(float x) {
    return x / (1.f + __expf(-x));
}

__device__ __forceinline__ void mfma_bf16(f32x4& d, const u32x4& a, const u32x4& b) {
    asm("v_mfma_f32_16x16x32_bf16 %0, %1, %2, %0" : "+v"(d) : "v"(a), "v"(b));
}

// ---------------- fp32 -> bf16 convert ----------------
__global__ __launch_bounds__(256) void cvt_bf16_kernel(const float* __restrict__ in,
                                                       unsigned short* __restrict__ out,
                                                       int n) {
    int i = blockIdx.x * 256 + threadIdx.x;
    if (i < n) out[i] = f2bf(in[i]);
}

// ---------------- bf16 MFMA GEMM: C[M][N] = A[M][K] * B[N][K]^T ----------------
// 128x128 tile, BK=32, 4 waves (2x2), 4x4 16x16x32 fragments per wave.
__global__ __launch_bounds__(256) void gemm_bf16_nt(const unsigned short* __restrict__ A,
                                                    const unsigned short* __restrict__ B,
                                                    float* __restrict__ C,
                                                    int M, int N, int K) {
    __shared__ unsigned short As[128 * 32];
    __shared__ unsigned short Bs[128 * 32];

    const int tid  = threadIdx.x;
    const int lane = tid & 63;
    const int wave = tid >> 6;
    const int wr = wave >> 1, wc = wave & 1;
    const int lrow = lane & 15, lkh = lane >> 4;   // row within frag, k-quarter

    const long m0 = (long)blockIdx.y * 128;
    const long n0 = (long)blockIdx.x * 128;

    const unsigned short* pa = A + (m0 + (tid >> 2)) * K + (tid & 3) * 8;
    const unsigned short* pb = B + (n0 + (tid >> 2)) * K + (tid & 3) * 8;
    const long half = (long)64 * K;

    f32x4 acc[4][4];
#pragma unroll
    for (int i = 0; i < 4; ++i)
#pragma unroll
        for (int j = 0; j < 4; ++j)
            acc[i][j] = (f32x4){0.f, 0.f, 0.f, 0.f};

    uint4 ra0 = *(const uint4*)(pa);
    uint4 ra1 = *(const uint4*)(pa + half);
    uint4 rb0 = *(const uint4*)(pb);
    uint4 rb1 = *(const uint4*)(pb + half);

    for (int k0 = 0; k0 < K; k0 += 32) {
        __syncthreads();
        *(uint4*)(As + tid * 8)        = ra0;
        *(uint4*)(As + 2048 + tid * 8) = ra1;
        *(uint4*)(Bs + tid * 8)        = rb0;
        *(uint4*)(Bs + 2048 + tid * 8) = rb1;
        __syncthreads();

        if (k0 + 32 < K) {   // prefetch next K-step (overlaps with MFMA below)
            ra0 = *(const uint4*)(pa + k0 + 32);
            ra1 = *(const uint4*)(pa + half + k0 + 32);
            rb0 = *(const uint4*)(pb + k0 + 32);
            rb1 = *(const uint4*)(pb + half + k0 + 32);
        }

        u32x4 af[4], bfr[4];
#pragma unroll
        for (int i = 0; i < 4; ++i)
            af[i] = *(const u32x4*)(As + (wr * 64 + i * 16 + lrow) * 32 + lkh * 8);
#pragma unroll
        for (int j = 0; j < 4; ++j)
            bfr[j] = *(const u32x4*)(Bs + (wc * 64 + j * 16 + lrow) * 32 + lkh * 8);

#pragma unroll
        for (int i = 0; i < 4; ++i)
#pragma unroll
            for (int j = 0; j < 4; ++j)
                mfma_bf16(acc[i][j], af[i], bfr[j]);
    }

    // XDL -> VALU read hazard guard around inline-asm MFMA
    asm volatile("s_nop 7\n\ts_nop 7" ::: "memory");

#pragma unroll
    for (int i = 0; i < 4; ++i)
#pragma unroll
        for (int j = 0; j < 4; ++j)
#pragma unroll
            for (int r = 0; r < 4; ++r) {
                long row = m0 + wr * 64 + i * 16 + lkh * 4 + r;
                long col = n0 + wc * 64 + j * 16 + lrow;
                C[row * (long)N + col] = acc[i][j][r];
            }
}

// ---------------- depthwise causal conv(4) + bias + SiLU ----------------
// xc[b,t,d] = silu( sum_j xz[b, t-3+j, d] * w[d][j] + bias[d] ),  xp = xz[:, :, 0:DI]
__global__ __launch_bounds__(256) void conv_silu_kernel(const float* __restrict__ xz,
                                                        const float* __restrict__ cw,
                                                        const float* __restrict__ cb,
                                                        float* __restrict__ xc) {
    int idx = blockIdx.x * 256 + threadIdx.x;     // BL * DI
    int d = idx & (DI - 1);
    int m = idx >> 11;
    int t = m & (LSEQ - 1);
    const float4 w = *(const float4*)(cw + 4 * d);
    const float* p = xz + (long)m * (2 * DI) + d;
    float s = cb[d];
    s += (t >= 3 ? p[-3 * 2 * DI] : 0.f) * w.x;
    s += (t >= 2 ? p[-2 * 2 * DI] : 0.f) * w.y;
    s += (t >= 1 ? p[-1 * 2 * DI] : 0.f) * w.z;
    s += p[0] * w.w;
    xc[(long)m * DI + d] = silu_f(s);
}

// ---------------- GEMM2 partials: xdbl[m][e] = sum_k xc[m][k] * Wx[e][k] ----------------
// K split 16 ways for occupancy; deterministic two-stage reduce (no atomics).
__global__ __launch_bounds__(256) void gemm2_part_kernel(const float* __restrict__ xc,
                                                         const float* __restrict__ Wx,
                                                         float* __restrict__ part) {
    const int r  = blockIdx.x * 256 + threadIdx.x;  // row 0..4095
    const int kc = blockIdx.y;                       // 0..15
    const int k0 = kc * 128;
    float acc[33];
#pragma unroll
    for (int e = 0; e < 33; ++e) acc[e] = 0.f;
    const float* xr = xc + (long)r * DI + k0;
#pragma unroll 2
    for (int kk = 0; kk < 128; kk += 8) {
        const float4 a  = *(const float4*)(xr + kk);
        const float4 bq = *(const float4*)(xr + kk + 4);
#pragma unroll
        for (int e = 0; e < 33; ++e) {
            const float* wp = Wx + e * DI + k0 + kk;   // wave-uniform -> scalar loads
            acc[e] += a.x * wp[0] + a.y * wp[1] + a.z * wp[2] + a.w * wp[3] +
                      bq.x * wp[4] + bq.y * wp[5] + bq.z * wp[6] + bq.w * wp[7];
        }
    }
    float* po = part + (long)kc * (BL * 33) + (long)r * 33;
#pragma unroll
    for (int e = 0; e < 33; ++e) po[e] = acc[e];
}

// reduce 16 partials; col 0 -> softplus -> delta; cols 1..32 -> BC[m][0..31]
__global__ __launch_bounds__(256) void gemm2_reduce_kernel(const float* __restrict__ part,
                                                           float* __restrict__ dlt,
                                                           float* __restrict__ BC) {
    int idx = blockIdx.x * 256 + threadIdx.x;
    if (idx >= BL * 33) return;
    float sum = 0.f;
#pragma unroll
    for (int i = 0; i < 16; ++i) sum += part[(long)i * (BL * 33) + idx];
    int m = idx / 33;
    int j = idx - m * 33;
    if (j == 0) dlt[m] = (sum > 20.f) ? sum : log1pf(expf(sum));
    else        BC[(long)m * 32 + (j - 1)] = sum;
}

// ---------------- selective scan ----------------
// lane = (channel-in-block g, state s); h kept in a register over all 2048 steps.
// LDS double-buffers 64-step chunks of {delta, B||C, u || silu(z)}.
// Writes ybf = bf16( y_t * silu(z) ) directly.
#define TCH 64
__global__ __launch_bounds__(256) void scan_kernel(const float* __restrict__ dl_,
                                                   const float* __restrict__ BC,
                                                   const float* __restrict__ xc,
                                                   const float* __restrict__ xz,
                                                   const float* __restrict__ A_log,
                                                   unsigned short* __restrict__ ybf) {
    __shared__ float sdl[2][TCH];
    __shared__ float sbc[2][TCH][32];   // [t][0..15]=B, [16..31]=C
    __shared__ float suz[2][TCH][32];   // [t][0..15]=u, [16..31]=silu(z)

    const int tid = threadIdx.x;
    const int g = tid >> 4, s = tid & 15;
    const int c0 = blockIdx.x * 16;       // first channel of block
    const int b  = c0 >> 11;
    const int d0 = c0 & (DI - 1);
    const int d  = d0 + g;
    const float A = -expf(A_log[d * DS + s]);
    const long mb = (long)b * LSEQ;

    const int tt4 = tid >> 2, jj4 = (tid & 3) * 4;

    float4 rb0, rb1, ru, rz;
    float  rd;

    // LD(0)
    {
        const long m0 = mb;
        rb0 = *(const float4*)(BC + m0 * 32 + tid * 4);
        rb1 = *(const float4*)(BC + m0 * 32 + (tid + 256) * 4);
        ru  = *(const float4*)(xc + (m0 + tt4) * DI + d0 + jj4);
        rz  = *(const float4*)(xz + (m0 + tt4) * (2 * DI) + DI + d0 + jj4);
        rd  = (tid < TCH) ? dl_[m0 + tid] : 0.f;
    }
    // ST(0)
    {
        *(float4*)(&sbc[0][0][0] + tid * 4)         = rb0;
        *(float4*)(&sbc[0][0][0] + (tid + 256) * 4) = rb1;
        *(float4*)(&suz[0][tt4][jj4]) = ru;
        float4 z4;
        z4.x = silu_f(rz.x); z4.y = silu_f(rz.y); z4.z = silu_f(rz.z); z4.w = silu_f(rz.w);
        *(float4*)(&suz[0][tt4][16 + jj4]) = z4;
        if (tid < TCH) sdl[0][tid] = rd;
    }

    float h = 0.f;
    const int NCH = LSEQ / TCH;
    for (int ch = 0; ch < NCH; ++ch) {
        const int cur = ch & 1;
        __syncthreads();

        if (ch + 1 < NCH) {   // issue next-chunk global loads early
            const long m0 = mb + (long)(ch + 1) * TCH;
            rb0 = *(const float4*)(BC + m0 * 32 + tid * 4);
            rb1 = *(const float4*)(BC + m0 * 32 + (tid + 256) * 4);
            ru  = *(const float4*)(xc + (m0 + tt4) * DI + d0 + jj4);
            rz  = *(const float4*)(xz + (m0 + tt4) * (2 * DI) + DI + d0 + jj4);
            rd  = (tid < TCH) ? dl_[m0 + tid] : 0.f;
        }

        const long mrow = mb + (long)ch * TCH;
#pragma unroll 4
        for (int tt = 0; tt < TCH; ++tt) {
            float dl = sdl[cur][tt];
            float Bv = sbc[cur][tt][s];
            float Cv = sbc[cur][tt][16 + s];
            float u  = suz[cur][tt][g];
            float dA = __expf(dl * A);
            h = fmaf(dA, h, dl * u * Bv);
            float p = h * Cv;
            p += __shfl_xor(p, 1);
            p += __shfl_xor(p, 2);
            p += __shfl_xor(p, 4);
            p += __shfl_xor(p, 8);
            if (s == 0) {
                float zs = suz[cur][tt][16 + g];
                ybf[(mrow + tt) * (long)DI + d] = f2bf(p * zs);
            }
        }

        if (ch + 1 < NCH) {   // write next chunk into the other buffer
            const int nxt = cur ^ 1;
            *(float4*)(&sbc[nxt][0][0] + tid * 4)         = rb0;
            *(float4*)(&sbc[nxt][0][0] + (tid + 256) * 4) = rb1;
            *(float4*)(&suz[nxt][tt4][jj4]) = ru;
            float4 z4;
            z4.x = silu_f(rz.x); z4.y = silu_f(rz.y); z4.z = silu_f(rz.z); z4.w = silu_f(rz.w);
            *(float4*)(&suz[nxt][tt4][16 + jj4]) = z4;
            if (tid < TCH) sdl[nxt][tid] = rd;
        }
    }
}

// ---------------- host launcher ----------------
extern "C" void kernel_launch(void* const* d_in, const int* in_sizes, int n_in,
                              void* d_out, int out_size, void* d_ws, size_t ws_size,
                              hipStream_t stream) {
    const float* x      = (const float*)d_in[0];   // [2,2048,1024]
    const float* W_in   = (const float*)d_in[1];   // [4096,1024]
    const float* conv_w = (const float*)d_in[2];   // [2048,1,4]
    const float* conv_b = (const float*)d_in[3];   // [2048]
    const float* A_log  = (const float*)d_in[4];   // [2048,16]
    const float* W_x    = (const float*)d_in[5];   // [33,2048]
    const float* W_out  = (const float*)d_in[6];   // [1024,2048]
    float* out = (float*)d_out;                    // [2,2048,1024]

    char* w = (char*)d_ws;
    unsigned short* xbf  = (unsigned short*)(w + 0);          //  8,388,608 B
    unsigned short* wbf  = (unsigned short*)(w + 8388608);    //  8,388,608 B
    float*          xz   = (float*)(w + 16777216);            // 67,108,864 B
    float*          xc   = (float*)(w + 83886080);            // 33,554,432 B
    float*          part = (float*)(w + 117440512);           //  8,650,752 B
    float*          dlt  = (float*)(w + 126091264);           //     16,384 B
    float*          BC   = (float*)(w + 126107648);           //    524,288 B
    unsigned short* ybf  = (unsigned short*)(w + 126631936);  // 16,777,216 B
    unsigned short* wobf = xbf;  // reuse x_bf16 region after GEMM1 (stream-ordered)

    // 1) converts
    cvt_bf16_kernel<<<dim3(16384), dim3(256), 0, stream>>>(x, xbf, BL * DM);
    cvt_bf16_kernel<<<dim3(16384), dim3(256), 0, stream>>>(W_in, wbf, 2 * DI * DM);
    // 2) xz = x @ W_in^T   (M=4096, N=4096, K=1024)
    gemm_bf16_nt<<<dim3(32, 32), dim3(256), 0, stream>>>(xbf, wbf, xz, BL, 2 * DI, DM);
    // 3) W_out -> bf16 (into released xbf region)
    cvt_bf16_kernel<<<dim3(8192), dim3(256), 0, stream>>>(W_out, wobf, DM * DI);
    // 4) depthwise conv + SiLU
    conv_silu_kernel<<<dim3((BL * DI) / 256), dim3(256), 0, stream>>>(xz, conv_w, conv_b, xc);
    // 5) xdbl partials + reduce/softplus split
    gemm2_part_kernel<<<dim3(16, 16), dim3(256), 0, stream>>>(xc, W_x, part);
    gemm2_reduce_kernel<<<dim3((BL * 33 + 255) / 256), dim3(256), 0, stream>>>(part, dlt, BC);
    // 6) selective scan (+ fused *silu(z), bf16 output)
    scan_kernel<<<dim3(BL / 16), dim3(256), 0, stream>>>(dlt, BC, xc, xz, A_log, ybf);
    // 7) out = y @ W_out^T   (M=4096, N=1024, K=2048)
    gemm_bf16_nt<<<dim3(8, 32), dim3(256), 0, stream>>>(ybf, wobf, out, BL, DM, DI);
}

// Round 2
// 354.350 us; speedup vs baseline: 1.7946x; 1.7946x over previous
//
#include <hip/hip_runtime.h>

// ---------------- problem constants ----------------
#define DM    1024      // D_MODEL
#define DS    16        // D_STATE
#define DI    2048      // D_INNER
#define LSEQ  2048      // SEQ
#define BL    4096      // BATCH * SEQ rows
#define NC    64        // scan chunks
#define CHK   32        // LSEQ / NC

typedef float        f32x4 __attribute__((ext_vector_type(4)));
typedef unsigned int u32x4 __attribute__((ext_vector_type(4)));

__device__ __forceinline__ unsigned short f2bf(float f) {
    unsigned int u = __float_as_uint(f);
    u += 0x7fffu + ((u >> 16) & 1u);      // round-to-nearest-even
    return (unsigned short)(u >> 16);
}

__device__ __forceinline__ float silu_f(float x) {
    return x / (1.f + __expf(-x));
}

__device__ __forceinline__ void mfma_bf16(f32x4& d, const u32x4& a, const u32x4& b) {
    asm("v_mfma_f32_16x16x32_bf16 %0, %1, %2, %0" : "+v"(d) : "v"(a), "v"(b));
}

__device__ __forceinline__ void gload16(const void* g, void* l) {
    __builtin_amdgcn_global_load_lds(
        (const __attribute__((address_space(1))) unsigned int*)g,
        (__attribute__((address_space(3))) unsigned int*)l, 16, 0, 0);
}

// ---------------- fp32 -> bf16 convert ----------------
__global__ __launch_bounds__(256) void cvt_bf16_kernel(const float* __restrict__ in,
                                                       unsigned short* __restrict__ out,
                                                       int n) {
    int i = blockIdx.x * 256 + threadIdx.x;
    if (i < n) out[i] = f2bf(in[i]);
}

// ---------------- bf16 MFMA GEMM: C[M][N] = A[M][K] * B[N][K]^T ----------------
// 128x128 tile, BK=32, 4 waves (2x2), 4x4 16x16x32 fragments per wave.
// m97-style: global_load_lds width-16 staging, 2-barrier K-loop.
__global__ __launch_bounds__(256) void gemm_bf16_nt(const unsigned short* __restrict__ A,
                                                    const unsigned short* __restrict__ B,
                                                    float* __restrict__ C,
                                                    int M, int N, int K) {
    __shared__ unsigned short As[128 * 32];
    __shared__ unsigned short Bs[128 * 32];

    const int tid  = threadIdx.x;
    const int lane = tid & 63;
    const int wave = tid >> 6;
    const int wr = wave >> 1, wc = wave & 1;
    const int lrow = lane & 15, lkh = lane >> 4;   // row within frag, k-quarter

    const long m0 = (long)blockIdx.y * 128;
    const long n0 = (long)blockIdx.x * 128;

    const unsigned short* pa = A + (m0 + (tid >> 2)) * K + (tid & 3) * 8;
    const unsigned short* pb = B + (n0 + (tid >> 2)) * K + (tid & 3) * 8;
    const long half = (long)64 * K;

    // LDS destinations: linear layout, wave-uniform base + lane*16 bytes
    char* AsB = (char*)As + wave * 1024;
    char* BsB = (char*)Bs + wave * 1024;

    f32x4 acc[4][4];
#pragma unroll
    for (int i = 0; i < 4; ++i)
#pragma unroll
        for (int j = 0; j < 4; ++j)
            acc[i][j] = (f32x4){0.f, 0.f, 0.f, 0.f};

    for (int k0 = 0; k0 < K; k0 += 32) {
        __syncthreads();   // previous tile's ds_reads done before overwrite
        gload16(pa + k0,        AsB);
        gload16(pa + half + k0, AsB + 4096);
        gload16(pb + k0,        BsB);
        gload16(pb + half + k0, BsB + 4096);
        __syncthreads();   // drains vmcnt(0) -> tile resident

        u32x4 af[4], bfr[4];
#pragma unroll
        for (int i = 0; i < 4; ++i)
            af[i] = *(const u32x4*)(As + (wr * 64 + i * 16 + lrow) * 32 + lkh * 8);
#pragma unroll
        for (int j = 0; j < 4; ++j)
            bfr[j] = *(const u32x4*)(Bs + (wc * 64 + j * 16 + lrow) * 32 + lkh * 8);

#pragma unroll
        for (int i = 0; i < 4; ++i)
#pragma unroll
            for (int j = 0; j < 4; ++j)
                mfma_bf16(acc[i][j], af[i], bfr[j]);
    }

    // XDL -> VALU read hazard guard around inline-asm MFMA
    asm volatile("s_nop 7\n\ts_nop 7" ::: "memory");

#pragma unroll
    for (int i = 0; i < 4; ++i)
#pragma unroll
        for (int j = 0; j < 4; ++j)
#pragma unroll
            for (int r = 0; r < 4; ++r) {
                long row = m0 + wr * 64 + i * 16 + lkh * 4 + r;
                long col = n0 + wc * 64 + j * 16 + lrow;
                C[row * (long)N + col] = acc[i][j][r];
            }
}

// ---------------- depthwise causal conv(4) + bias + SiLU ----------------
__global__ __launch_bounds__(256) void conv_silu_kernel(const float* __restrict__ xz,
                                                        const float* __restrict__ cw,
                                                        const float* __restrict__ cb,
                                                        float* __restrict__ xc) {
    int idx = blockIdx.x * 256 + threadIdx.x;     // BL * DI
    int d = idx & (DI - 1);
    int m = idx >> 11;
    int t = m & (LSEQ - 1);
    const float4 w = *(const float4*)(cw + 4 * d);
    const float* p = xz + (long)m * (2 * DI) + d;
    float s = cb[d];
    s += (t >= 3 ? p[-3 * 2 * DI] : 0.f) * w.x;
    s += (t >= 2 ? p[-2 * 2 * DI] : 0.f) * w.y;
    s += (t >= 1 ? p[-1 * 2 * DI] : 0.f) * w.z;
    s += p[0] * w.w;
    xc[(long)m * DI + d] = silu_f(s);
}

// ---------------- GEMM2 partials: xdbl[m][e] = sum_k xc[m][k] * Wx[e][k] ----------------
__global__ __launch_bounds__(256) void gemm2_part_kernel(const float* __restrict__ xc,
                                                         const float* __restrict__ Wx,
                                                         float* __restrict__ part) {
    const int r  = blockIdx.x * 256 + threadIdx.x;  // row 0..4095
    const int kc = blockIdx.y;                       // 0..15
    const int k0 = kc * 128;
    float acc[33];
#pragma unroll
    for (int e = 0; e < 33; ++e) acc[e] = 0.f;
    const float* xr = xc + (long)r * DI + k0;
#pragma unroll 2
    for (int kk = 0; kk < 128; kk += 8) {
        const float4 a  = *(const float4*)(xr + kk);
        const float4 bq = *(const float4*)(xr + kk + 4);
#pragma unroll
        for (int e = 0; e < 33; ++e) {
            const float* wp = Wx + e * DI + k0 + kk;   // wave-uniform -> scalar loads
            acc[e] += a.x * wp[0] + a.y * wp[1] + a.z * wp[2] + a.w * wp[3] +
                      bq.x * wp[4] + bq.y * wp[5] + bq.z * wp[6] + bq.w * wp[7];
        }
    }
    float* po = part + (long)kc * (BL * 33) + (long)r * 33;
#pragma unroll
    for (int e = 0; e < 33; ++e) po[e] = acc[e];
}

__global__ __launch_bounds__(256) void gemm2_reduce_kernel(const float* __restrict__ part,
                                                           float* __restrict__ dlt,
                                                           float* __restrict__ BC) {
    int idx = blockIdx.x * 256 + threadIdx.x;
    if (idx >= BL * 33) return;
    float sum = 0.f;
#pragma unroll
    for (int i = 0; i < 16; ++i) sum += part[(long)i * (BL * 33) + idx];
    int m = idx / 33;
    int j = idx - m * 33;
    if (j == 0) dlt[m] = (sum > 20.f) ? sum : log1pf(expf(sum));
    else        BC[(long)m * 32 + (j - 1)] = sum;
}

// ---------------- selective scan, chunked-parallel ----------------
// Layout: lane owns channel d (16 states in registers). No cross-lane ops.
// pass1: per chunk c, per (b,d): P[s] = prod dA, S[s] = local scan from 0.
// pass2: sequential combine over chunks; S_ becomes h0-per-chunk in place.
// pass3: re-run each chunk from its h0, emit y*silu(z) as bf16.

__global__ __launch_bounds__(256) void scan_pass1(const float* __restrict__ dlt,
                                                  const float* __restrict__ BC,
                                                  const float* __restrict__ xc,
                                                  const float* __restrict__ A_log,
                                                  float* __restrict__ P_,
                                                  float* __restrict__ S_) {
    const int c  = blockIdx.x;                        // chunk 0..NC-1
    const int ch = blockIdx.y * 256 + threadIdx.x;    // channel 0..4095
    const int b  = ch >> 11;
    const int d  = ch & (DI - 1);
    const long m0 = (long)b * LSEQ + (long)c * CHK;

    float A[16], h[16], P[16];
#pragma unroll
    for (int s = 0; s < 16; ++s) {
        A[s] = -__expf(A_log[d * 16 + s]);
        h[s] = 0.f;
        P[s] = 1.f;
    }
    const float* xr = xc + m0 * DI + d;
    const float* br = BC + m0 * 32;
    const float* dr = dlt + m0;

#pragma unroll 2
    for (int t = 0; t < CHK; ++t) {
        float dl = dr[t];
        float u  = xr[(long)t * DI];
        float du = dl * u;
        float Bv[16];
        *(float4*)&Bv[0]  = *(const float4*)(br + t * 32 + 0);
        *(float4*)&Bv[4]  = *(const float4*)(br + t * 32 + 4);
        *(float4*)&Bv[8]  = *(const float4*)(br + t * 32 + 8);
        *(float4*)&Bv[12] = *(const float4*)(br + t * 32 + 12);
#pragma unroll
        for (int s = 0; s < 16; ++s) {
            float dA = __expf(dl * A[s]);
            P[s] *= dA;
            h[s] = fmaf(dA, h[s], du * Bv[s]);
        }
    }
    float* pp = P_ + ((long)c * 4096 + ch) * 16;
    float* sp = S_ + ((long)c * 4096 + ch) * 16;
#pragma unroll
    for (int q = 0; q < 4; ++q) {
        *(float4*)(pp + q * 4) = (float4){P[q*4], P[q*4+1], P[q*4+2], P[q*4+3]};
        *(float4*)(sp + q * 4) = (float4){h[q*4], h[q*4+1], h[q*4+2], h[q*4+3]};
    }
}

__global__ __launch_bounds__(256) void scan_pass2(const float* __restrict__ P_,
                                                  float* __restrict__ S_) {
    const long idx = (long)blockIdx.x * 256 + threadIdx.x;  // (ch*16+s), 0..65535
    float h = 0.f;
#pragma unroll 4
    for (int c = 0; c < NC; ++c) {
        float p = P_[(long)c * 65536 + idx];
        float s = S_[(long)c * 65536 + idx];
        S_[(long)c * 65536 + idx] = h;        // h0 entering chunk c
        h = fmaf(p, h, s);
    }
}

__global__ __launch_bounds__(256) void scan_pass3(const float* __restrict__ dlt,
                                                  const float* __restrict__ BC,
                                                  const float* __restrict__ xc,
                                                  const float* __restrict__ xz,
                                                  const float* __restrict__ A_log,
                                                  const float* __restrict__ H0,
                                                  unsigned short* __restrict__ ybf) {
    const int c  = blockIdx.x;
    const int ch = blockIdx.y * 256 + threadIdx.x;
    const int b  = ch >> 11;
    const int d  = ch & (DI - 1);
    const long m0 = (long)b * LSEQ + (long)c * CHK;

    float A[16], h[16];
    const float* h0p = H0 + ((long)c * 4096 + ch) * 16;
#pragma unroll
    for (int s = 0; s < 16; ++s) {
        A[s] = -__expf(A_log[d * 16 + s]);
        h[s] = h0p[s];
    }
    const float* xr = xc + m0 * DI + d;
    const float* zr = xz + m0 * (2 * DI) + DI + d;
    const float* br = BC + m0 * 32;
    const float* dr = dlt + m0;
    unsigned short* yr = ybf + m0 * DI + d;

#pragma unroll 2
    for (int t = 0; t < CHK; ++t) {
        float dl = dr[t];
        float u  = xr[(long)t * DI];
        float z  = zr[(long)t * 2 * DI];
        float du = dl * u;
        float Bv[16], Cv[16];
        *(float4*)&Bv[0]  = *(const float4*)(br + t * 32 + 0);
        *(float4*)&Bv[4]  = *(const float4*)(br + t * 32 + 4);
        *(float4*)&Bv[8]  = *(const float4*)(br + t * 32 + 8);
        *(float4*)&Bv[12] = *(const float4*)(br + t * 32 + 12);
        *(float4*)&Cv[0]  = *(const float4*)(br + t * 32 + 16);
        *(float4*)&Cv[4]  = *(const float4*)(br + t * 32 + 20);
        *(float4*)&Cv[8]  = *(const float4*)(br + t * 32 + 24);
        *(float4*)&Cv[12] = *(const float4*)(br + t * 32 + 28);
        float y = 0.f;
#pragma unroll
        for (int s = 0; s < 16; ++s) {
            float dA = __expf(dl * A[s]);
            h[s] = fmaf(dA, h[s], du * Bv[s]);
            y = fmaf(h[s], Cv[s], y);
        }
        yr[(long)t * DI] = f2bf(y * silu_f(z));
    }
}

// ---------------- host launcher ----------------
extern "C" void kernel_launch(void* const* d_in, const int* in_sizes, int n_in,
                              void* d_out, int out_size, void* d_ws, size_t ws_size,
                              hipStream_t stream) {
    const float* x      = (const float*)d_in[0];   // [2,2048,1024]
    const float* W_in   = (const float*)d_in[1];   // [4096,1024]
    const float* conv_w = (const float*)d_in[2];   // [2048,1,4]
    const float* conv_b = (const float*)d_in[3];   // [2048]
    const float* A_log  = (const float*)d_in[4];   // [2048,16]
    const float* W_x    = (const float*)d_in[5];   // [33,2048]
    const float* W_out  = (const float*)d_in[6];   // [1024,2048]
    float* out = (float*)d_out;                    // [2,2048,1024]

    char* w = (char*)d_ws;
    unsigned short* xbf  = (unsigned short*)(w + 0);          //  8,388,608 B
    unsigned short* wbf  = (unsigned short*)(w + 8388608);    //  8,388,608 B
    float*          xz   = (float*)(w + 16777216);            // 67,108,864 B
    float*          xc   = (float*)(w + 83886080);            // 33,554,432 B
    float*          part = (float*)(w + 117440512);           //  8,650,752 B
    float*          dlt  = (float*)(w + 126091264);           //     16,384 B
    float*          BC   = (float*)(w + 126107648);           //    524,288 B
    unsigned short* ybf  = (unsigned short*)(w + 126631936);  // 16,777,216 B
    float*          P_   = (float*)(w + 143409152);           // 16,777,216 B
    float*          S_   = (float*)(w + 160186368);           // 16,777,216 B
    unsigned short* wobf = xbf;  // reuse x_bf16 region after GEMM1 (stream-ordered)

    // 1) converts
    cvt_bf16_kernel<<<dim3(16384), dim3(256), 0, stream>>>(x, xbf, BL * DM);
    cvt_bf16_kernel<<<dim3(16384), dim3(256), 0, stream>>>(W_in, wbf, 2 * DI * DM);
    // 2) xz = x @ W_in^T   (M=4096, N=4096, K=1024)
    gemm_bf16_nt<<<dim3(32, 32), dim3(256), 0, stream>>>(xbf, wbf, xz, BL, 2 * DI, DM);
    // 3) W_out -> bf16 (into released xbf region)
    cvt_bf16_kernel<<<dim3(8192), dim3(256), 0, stream>>>(W_out, wobf, DM * DI);
    // 4) depthwise conv + SiLU
    conv_silu_kernel<<<dim3((BL * DI) / 256), dim3(256), 0, stream>>>(xz, conv_w, conv_b, xc);
    // 5) xdbl partials + reduce/softplus split
    gemm2_part_kernel<<<dim3(16, 16), dim3(256), 0, stream>>>(xc, W_x, part);
    gemm2_reduce_kernel<<<dim3((BL * 33 + 255) / 256), dim3(256), 0, stream>>>(part, dlt, BC);
    // 6) chunked selective scan
    scan_pass1<<<dim3(NC, 16), dim3(256), 0, stream>>>(dlt, BC, xc, A_log, P_, S_);
    scan_pass2<<<dim3(256), dim3(256), 0, stream>>>(P_, S_);
    scan_pass3<<<dim3(NC, 16), dim3(256), 0, stream>>>(dlt, BC, xc, xz, A_log, S_, ybf);
    // 7) out = y @ W_out^T   (M=4096, N=1024, K=2048)
    gemm_bf16_nt<<<dim3(8, 32), dim3(256), 0, stream>>>(ybf, wobf, out, BL, DM, DI);
}

// Round 3
// 286.517 us; speedup vs baseline: 2.2195x; 1.2367x over previous
//
#include <hip/hip_runtime.h>

// ---------------- problem constants ----------------
#define DM    1024      // D_MODEL
#define DS    16        // D_STATE
#define DI    2048      // D_INNER
#define LSEQ  2048      // SEQ
#define BL    4096      // BATCH * SEQ rows
#define NC    64        // scan chunks
#define CHK   32        // LSEQ / NC

typedef float        f32x4 __attribute__((ext_vector_type(4)));
typedef unsigned int u32x4 __attribute__((ext_vector_type(4)));

__device__ __forceinline__ unsigned short f2bf(float f) {
    unsigned int u = __float_as_uint(f);
    u += 0x7fffu + ((u >> 16) & 1u);      // round-to-nearest-even
    return (unsigned short)(u >> 16);
}

__device__ __forceinline__ float silu_f(float x) {
    return x / (1.f + __expf(-x));
}

__device__ __forceinline__ void mfma_bf16(f32x4& d, const u32x4& a, const u32x4& b) {
    asm("v_mfma_f32_16x16x32_bf16 %0, %1, %2, %0" : "+v"(d) : "v"(a), "v"(b));
}

__device__ __forceinline__ void gload16(const void* g, void* l) {
    __builtin_amdgcn_global_load_lds(
        (const __attribute__((address_space(1))) unsigned int*)g,
        (__attribute__((address_space(3))) unsigned int*)l, 16, 0, 0);
}

// ---------------- fp32 -> bf16 convert ----------------
__global__ __launch_bounds__(256) void cvt_bf16_kernel(const float* __restrict__ in,
                                                       unsigned short* __restrict__ out,
                                                       int n) {
    int i = blockIdx.x * 256 + threadIdx.x;
    if (i < n) out[i] = f2bf(in[i]);
}

// W_x [33][2048] -> zero-padded bf16 [128][2048]
__global__ __launch_bounds__(256) void wx_pad_kernel(const float* __restrict__ Wx,
                                                     unsigned short* __restrict__ out) {
    int i = blockIdx.x * 256 + threadIdx.x;        // 128*2048
    int e = i >> 11;
    out[i] = (e < 33) ? f2bf(Wx[i]) : (unsigned short)0;
}

// ---------------- bf16 MFMA GEMM: C[M][N] = A[M][K] * B[N][K]^T ----------------
// 128x128 tile, BK=32, 4 waves (2x2), 4x4 16x16x32 fragments per wave.
// m97-style: global_load_lds width-16 staging, 2-barrier K-loop.
__global__ __launch_bounds__(256) void gemm_bf16_nt(const unsigned short* __restrict__ A,
                                                    const unsigned short* __restrict__ B,
                                                    float* __restrict__ C,
                                                    int M, int N, int K) {
    __shared__ unsigned short As[128 * 32];
    __shared__ unsigned short Bs[128 * 32];

    const int tid  = threadIdx.x;
    const int lane = tid & 63;
    const int wave = tid >> 6;
    const int wr = wave >> 1, wc = wave & 1;
    const int lrow = lane & 15, lkh = lane >> 4;   // row within frag, k-quarter

    const long m0 = (long)blockIdx.y * 128;
    const long n0 = (long)blockIdx.x * 128;

    const unsigned short* pa = A + (m0 + (tid >> 2)) * K + (tid & 3) * 8;
    const unsigned short* pb = B + (n0 + (tid >> 2)) * K + (tid & 3) * 8;
    const long half = (long)64 * K;

    // LDS destinations: linear layout, wave-uniform base + lane*16 bytes
    char* AsB = (char*)As + wave * 1024;
    char* BsB = (char*)Bs + wave * 1024;

    f32x4 acc[4][4];
#pragma unroll
    for (int i = 0; i < 4; ++i)
#pragma unroll
        for (int j = 0; j < 4; ++j)
            acc[i][j] = (f32x4){0.f, 0.f, 0.f, 0.f};

    for (int k0 = 0; k0 < K; k0 += 32) {
        __syncthreads();   // previous tile's ds_reads done before overwrite
        gload16(pa + k0,        AsB);
        gload16(pa + half + k0, AsB + 4096);
        gload16(pb + k0,        BsB);
        gload16(pb + half + k0, BsB + 4096);
        __syncthreads();   // drains vmcnt(0) -> tile resident

        u32x4 af[4], bfr[4];
#pragma unroll
        for (int i = 0; i < 4; ++i)
            af[i] = *(const u32x4*)(As + (wr * 64 + i * 16 + lrow) * 32 + lkh * 8);
#pragma unroll
        for (int j = 0; j < 4; ++j)
            bfr[j] = *(const u32x4*)(Bs + (wc * 64 + j * 16 + lrow) * 32 + lkh * 8);

#pragma unroll
        for (int i = 0; i < 4; ++i)
#pragma unroll
            for (int j = 0; j < 4; ++j)
                mfma_bf16(acc[i][j], af[i], bfr[j]);
    }

    // XDL -> VALU read hazard guard around inline-asm MFMA
    asm volatile("s_nop 7\n\ts_nop 7" ::: "memory");

#pragma unroll
    for (int i = 0; i < 4; ++i)
#pragma unroll
        for (int j = 0; j < 4; ++j)
#pragma unroll
            for (int r = 0; r < 4; ++r) {
                long row = m0 + wr * 64 + i * 16 + lkh * 4 + r;
                long col = n0 + wc * 64 + j * 16 + lrow;
                C[row * (long)N + col] = acc[i][j][r];
            }
}

// ---------------- depthwise causal conv(4) + bias + SiLU (+ bf16 copy) --------
__global__ __launch_bounds__(256) void conv_silu_kernel(const float* __restrict__ xz,
                                                        const float* __restrict__ cw,
                                                        const float* __restrict__ cb,
                                                        float* __restrict__ xc,
                                                        unsigned short* __restrict__ xcbf) {
    int idx = blockIdx.x * 256 + threadIdx.x;     // BL * DI
    int d = idx & (DI - 1);
    int m = idx >> 11;
    int t = m & (LSEQ - 1);
    const float4 w = *(const float4*)(cw + 4 * d);
    const float* p = xz + (long)m * (2 * DI) + d;
    float s = cb[d];
    s += (t >= 3 ? p[-3 * 2 * DI] : 0.f) * w.x;
    s += (t >= 2 ? p[-2 * 2 * DI] : 0.f) * w.y;
    s += (t >= 1 ? p[-1 * 2 * DI] : 0.f) * w.z;
    s += p[0] * w.w;
    float v = silu_f(s);
    xc[(long)m * DI + d] = v;
    xcbf[(long)m * DI + d] = f2bf(v);
}

// xdbl[4096][128] -> softplus(col0)=dlt, cols 1..32 -> BC
__global__ __launch_bounds__(256) void xdbl_reduce_kernel(const float* __restrict__ xdbl,
                                                          float* __restrict__ dlt,
                                                          float* __restrict__ BC) {
    int idx = blockIdx.x * 256 + threadIdx.x;     // BL * 33
    if (idx >= BL * 33) return;
    int m = idx / 33;
    int j = idx - m * 33;
    float v = xdbl[(long)m * 128 + j];
    if (j == 0) dlt[m] = (v > 20.f) ? v : log1pf(expf(v));
    else        BC[(long)m * 32 + (j - 1)] = v;
}

// ---------------- selective scan, chunked-parallel ----------------
// Layout: lane owns channel d (16 states in registers). No cross-lane ops.
__global__ __launch_bounds__(256) void scan_pass1(const float* __restrict__ dlt,
                                                  const float* __restrict__ BC,
                                                  const float* __restrict__ xc,
                                                  const float* __restrict__ A_log,
                                                  float* __restrict__ P_,
                                                  float* __restrict__ S_) {
    const int c  = blockIdx.x;                        // chunk 0..NC-1
    const int ch = blockIdx.y * 256 + threadIdx.x;    // channel 0..4095
    const int b  = ch >> 11;
    const int d  = ch & (DI - 1);
    const long m0 = (long)b * LSEQ + (long)c * CHK;

    float A[16], h[16], P[16];
#pragma unroll
    for (int s = 0; s < 16; ++s) {
        A[s] = -__expf(A_log[d * 16 + s]);
        h[s] = 0.f;
        P[s] = 1.f;
    }
    const float* xr = xc + m0 * DI + d;
    const float* br = BC + m0 * 32;
    const float* dr = dlt + m0;

#pragma unroll 2
    for (int t = 0; t < CHK; ++t) {
        float dl = dr[t];
        float u  = xr[(long)t * DI];
        float du = dl * u;
        float Bv[16];
        *(float4*)&Bv[0]  = *(const float4*)(br + t * 32 + 0);
        *(float4*)&Bv[4]  = *(const float4*)(br + t * 32 + 4);
        *(float4*)&Bv[8]  = *(const float4*)(br + t * 32 + 8);
        *(float4*)&Bv[12] = *(const float4*)(br + t * 32 + 12);
#pragma unroll
        for (int s = 0; s < 16; ++s) {
            float dA = __expf(dl * A[s]);
            P[s] *= dA;
            h[s] = fmaf(dA, h[s], du * Bv[s]);
        }
    }
    float* pp = P_ + ((long)c * 4096 + ch) * 16;
    float* sp = S_ + ((long)c * 4096 + ch) * 16;
#pragma unroll
    for (int q = 0; q < 4; ++q) {
        *(float4*)(pp + q * 4) = (float4){P[q*4], P[q*4+1], P[q*4+2], P[q*4+3]};
        *(float4*)(sp + q * 4) = (float4){h[q*4], h[q*4+1], h[q*4+2], h[q*4+3]};
    }
}

// sequential combine over chunks; batched prefetch of 8 to hide latency.
__global__ __launch_bounds__(256) void scan_pass2(const float* __restrict__ P_,
                                                  float* __restrict__ S_) {
    const long idx = (long)blockIdx.x * 256 + threadIdx.x;  // (ch*16+s), 0..65535
    float h = 0.f;
    for (int c0 = 0; c0 < NC; c0 += 8) {
        float p[8], s[8];
#pragma unroll
        for (int i = 0; i < 8; ++i) {
            p[i] = P_[(long)(c0 + i) * 65536 + idx];
            s[i] = S_[(long)(c0 + i) * 65536 + idx];
        }
#pragma unroll
        for (int i = 0; i < 8; ++i) {
            S_[(long)(c0 + i) * 65536 + idx] = h;   // h0 entering chunk c0+i
            h = fmaf(p[i], h, s[i]);
        }
    }
}

__global__ __launch_bounds__(256) void scan_pass3(const float* __restrict__ dlt,
                                                  const float* __restrict__ BC,
                                                  const float* __restrict__ xc,
                                                  const float* __restrict__ xz,
                                                  const float* __restrict__ A_log,
                                                  const float* __restrict__ H0,
                                                  unsigned short* __restrict__ ybf) {
    const int c  = blockIdx.x;
    const int ch = blockIdx.y * 256 + threadIdx.x;
    const int b  = ch >> 11;
    const int d  = ch & (DI - 1);
    const long m0 = (long)b * LSEQ + (long)c * CHK;

    float A[16], h[16];
    const float* h0p = H0 + ((long)c * 4096 + ch) * 16;
#pragma unroll
    for (int s = 0; s < 16; ++s) {
        A[s] = -__expf(A_log[d * 16 + s]);
        h[s] = h0p[s];
    }
    const float* xr = xc + m0 * DI + d;
    const float* zr = xz + m0 * (2 * DI) + DI + d;
    const float* br = BC + m0 * 32;
    const float* dr = dlt + m0;
    unsigned short* yr = ybf + m0 * DI + d;

#pragma unroll 2
    for (int t = 0; t < CHK; ++t) {
        float dl = dr[t];
        float u  = xr[(long)t * DI];
        float z  = zr[(long)t * 2 * DI];
        float du = dl * u;
        float Bv[16], Cv[16];
        *(float4*)&Bv[0]  = *(const float4*)(br + t * 32 + 0);
        *(float4*)&Bv[4]  = *(const float4*)(br + t * 32 + 4);
        *(float4*)&Bv[8]  = *(const float4*)(br + t * 32 + 8);
        *(float4*)&Bv[12] = *(const float4*)(br + t * 32 + 12);
        *(float4*)&Cv[0]  = *(const float4*)(br + t * 32 + 16);
        *(float4*)&Cv[4]  = *(const float4*)(br + t * 32 + 20);
        *(float4*)&Cv[8]  = *(const float4*)(br + t * 32 + 24);
        *(float4*)&Cv[12] = *(const float4*)(br + t * 32 + 28);
        float y = 0.f;
#pragma unroll
        for (int s = 0; s < 16; ++s) {
            float dA = __expf(dl * A[s]);
            h[s] = fmaf(dA, h[s], du * Bv[s]);
            y = fmaf(h[s], Cv[s], y);
        }
        yr[(long)t * DI] = f2bf(y * silu_f(z));
    }
}

// ---------------- host launcher ----------------
extern "C" void kernel_launch(void* const* d_in, const int* in_sizes, int n_in,
                              void* d_out, int out_size, void* d_ws, size_t ws_size,
                              hipStream_t stream) {
    const float* x      = (const float*)d_in[0];   // [2,2048,1024]
    const float* W_in   = (const float*)d_in[1];   // [4096,1024]
    const float* conv_w = (const float*)d_in[2];   // [2048,1,4]
    const float* conv_b = (const float*)d_in[3];   // [2048]
    const float* A_log  = (const float*)d_in[4];   // [2048,16]
    const float* W_x    = (const float*)d_in[5];   // [33,2048]
    const float* W_out  = (const float*)d_in[6];   // [1024,2048]
    float* out = (float*)d_out;                    // [2,2048,1024]

    char* w = (char*)d_ws;
    unsigned short* xbf  = (unsigned short*)(w + 0);          //  8,388,608 B
    unsigned short* wbf  = (unsigned short*)(w + 8388608);    //  8,388,608 B
    float*          xz   = (float*)(w + 16777216);            // 67,108,864 B
    float*          xc   = (float*)(w + 83886080);            // 33,554,432 B
    unsigned short* xcbf = (unsigned short*)(w + 117440512);  // 16,777,216 B
    float*          dlt  = (float*)(w + 134217728);           //     16,384 B
    float*          BC   = (float*)(w + 134234112);           //    524,288 B
    float*          P_   = (float*)(w + 134758400);           // 16,777,216 B
    float*          S_   = (float*)(w + 151535616);           // 16,777,216 B  (end 168,312,832)

    // regions reused after gemm1 (stream-ordered):
    unsigned short* wobf = xbf;                               // W_out bf16 (4.2 MB)
    float*          xdbl = (float*)(w + 8388608);             // [4096][128] f32 (2 MB, over wbf)
    unsigned short* wxbf = (unsigned short*)(w + 10485760);   // [128][2048] bf16 (0.5 MB, over wbf)
    unsigned short* ybf  = (unsigned short*)P_;               // y*silu(z) bf16 (over dead P_)

    // 1) converts
    cvt_bf16_kernel<<<dim3(16384), dim3(256), 0, stream>>>(x, xbf, BL * DM);
    cvt_bf16_kernel<<<dim3(16384), dim3(256), 0, stream>>>(W_in, wbf, 2 * DI * DM);
    // 2) xz = x @ W_in^T   (M=4096, N=4096, K=1024)
    gemm_bf16_nt<<<dim3(32, 32), dim3(256), 0, stream>>>(xbf, wbf, xz, BL, 2 * DI, DM);
    // 3) weight conversions into released regions
    cvt_bf16_kernel<<<dim3(8192), dim3(256), 0, stream>>>(W_out, wobf, DM * DI);
    wx_pad_kernel<<<dim3(1024), dim3(256), 0, stream>>>(W_x, wxbf);
    // 4) depthwise conv + SiLU (+ bf16 copy for gemm2)
    conv_silu_kernel<<<dim3((BL * DI) / 256), dim3(256), 0, stream>>>(xz, conv_w, conv_b, xc, xcbf);
    // 5) xdbl = xc @ W_x^T via MFMA (N padded to 128), then softplus/split
    gemm_bf16_nt<<<dim3(1, 32), dim3(256), 0, stream>>>(xcbf, wxbf, xdbl, BL, 128, DI);
    xdbl_reduce_kernel<<<dim3(528), dim3(256), 0, stream>>>(xdbl, dlt, BC);
    // 6) chunked selective scan
    scan_pass1<<<dim3(NC, 16), dim3(256), 0, stream>>>(dlt, BC, xc, A_log, P_, S_);
    scan_pass2<<<dim3(256), dim3(256), 0, stream>>>(P_, S_);
    scan_pass3<<<dim3(NC, 16), dim3(256), 0, stream>>>(dlt, BC, xc, xz, A_log, S_, ybf);
    // 7) out = y @ W_out^T   (M=4096, N=1024, K=2048)
    gemm_bf16_nt<<<dim3(8, 32), dim3(256), 0, stream>>>(ybf, wobf, out, BL, DM, DI);
}

// Round 4
// 245.010 us; speedup vs baseline: 2.5955x; 1.1694x over previous
//
#include <hip/hip_runtime.h>

// ---------------- problem constants ----------------
#define DM    1024      // D_MODEL
#define DS    16        // D_STATE
#define DI    2048      // D_INNER
#define LSEQ  2048      // SEQ
#define BL    4096      // BATCH * SEQ rows
#define NC    64        // scan chunks
#define CHK   32        // LSEQ / NC

typedef float        f32x4  __attribute__((ext_vector_type(4)));
typedef float        f32x16 __attribute__((ext_vector_type(16)));
typedef unsigned int u32x4  __attribute__((ext_vector_type(4)));

__device__ __forceinline__ unsigned short f2bf(float f) {
    unsigned int u = __float_as_uint(f);
    u += 0x7fffu + ((u >> 16) & 1u);      // round-to-nearest-even
    return (unsigned short)(u >> 16);
}

__device__ __forceinline__ float bf2f(unsigned short u) {
    return __uint_as_float((unsigned int)u << 16);
}

__device__ __forceinline__ float silu_f(float x) {
    return x / (1.f + __expf(-x));
}

__device__ __forceinline__ void mfma_bf16(f32x4& d, const u32x4& a, const u32x4& b) {
    asm("v_mfma_f32_16x16x32_bf16 %0, %1, %2, %0" : "+v"(d) : "v"(a), "v"(b));
}

__device__ __forceinline__ void gload16(const void* g, void* l) {
    __builtin_amdgcn_global_load_lds(
        (const __attribute__((address_space(1))) unsigned int*)g,
        (__attribute__((address_space(3))) unsigned int*)l, 16, 0, 0);
}

// ---------------- fp32 -> bf16 convert ----------------
__global__ __launch_bounds__(256) void cvt_bf16_kernel(const float* __restrict__ in,
                                                       unsigned short* __restrict__ out,
                                                       int n) {
    int i = blockIdx.x * 256 + threadIdx.x;
    if (i < n) out[i] = f2bf(in[i]);
}

// W_x [33][2048] -> zero-padded bf16 [128][2048]
__global__ __launch_bounds__(256) void wx_pad_kernel(const float* __restrict__ Wx,
                                                     unsigned short* __restrict__ out) {
    int i = blockIdx.x * 256 + threadIdx.x;        // 128*2048
    int e = i >> 11;
    out[i] = (e < 33) ? f2bf(Wx[i]) : (unsigned short)0;
}

// ---------------- bf16 MFMA GEMM: C[M][N] = A[M][K] * B[N][K]^T ----------------
__global__ __launch_bounds__(256) void gemm_bf16_nt(const unsigned short* __restrict__ A,
                                                    const unsigned short* __restrict__ B,
                                                    float* __restrict__ C,
                                                    int M, int N, int K) {
    __shared__ unsigned short As[128 * 32];
    __shared__ unsigned short Bs[128 * 32];

    const int tid  = threadIdx.x;
    const int lane = tid & 63;
    const int wave = tid >> 6;
    const int wr = wave >> 1, wc = wave & 1;
    const int lrow = lane & 15, lkh = lane >> 4;

    const long m0 = (long)blockIdx.y * 128;
    const long n0 = (long)blockIdx.x * 128;

    const unsigned short* pa = A + (m0 + (tid >> 2)) * K + (tid & 3) * 8;
    const unsigned short* pb = B + (n0 + (tid >> 2)) * K + (tid & 3) * 8;
    const long half = (long)64 * K;

    char* AsB = (char*)As + wave * 1024;
    char* BsB = (char*)Bs + wave * 1024;

    f32x4 acc[4][4];
#pragma unroll
    for (int i = 0; i < 4; ++i)
#pragma unroll
        for (int j = 0; j < 4; ++j)
            acc[i][j] = (f32x4){0.f, 0.f, 0.f, 0.f};

    for (int k0 = 0; k0 < K; k0 += 32) {
        __syncthreads();
        gload16(pa + k0,        AsB);
        gload16(pa + half + k0, AsB + 4096);
        gload16(pb + k0,        BsB);
        gload16(pb + half + k0, BsB + 4096);
        __syncthreads();

        u32x4 af[4], bfr[4];
#pragma unroll
        for (int i = 0; i < 4; ++i)
            af[i] = *(const u32x4*)(As + (wr * 64 + i * 16 + lrow) * 32 + lkh * 8);
#pragma unroll
        for (int j = 0; j < 4; ++j)
            bfr[j] = *(const u32x4*)(Bs + (wc * 64 + j * 16 + lrow) * 32 + lkh * 8);

#pragma unroll
        for (int i = 0; i < 4; ++i)
#pragma unroll
            for (int j = 0; j < 4; ++j)
                mfma_bf16(acc[i][j], af[i], bfr[j]);
    }

    asm volatile("s_nop 7\n\ts_nop 7" ::: "memory");

#pragma unroll
    for (int i = 0; i < 4; ++i)
#pragma unroll
        for (int j = 0; j < 4; ++j)
#pragma unroll
            for (int r = 0; r < 4; ++r) {
                long row = m0 + wr * 64 + i * 16 + lkh * 4 + r;
                long col = n0 + wc * 64 + j * 16 + lrow;
                C[row * (long)N + col] = acc[i][j][r];
            }
}

// ---------------- depthwise causal conv(4) + bias + SiLU -> bf16 ----------------
__global__ __launch_bounds__(256) void conv_silu_kernel(const float* __restrict__ xz,
                                                        const float* __restrict__ cw,
                                                        const float* __restrict__ cb,
                                                        unsigned short* __restrict__ xcbf) {
    int idx = blockIdx.x * 256 + threadIdx.x;     // BL * DI
    int d = idx & (DI - 1);
    int m = idx >> 11;
    int t = m & (LSEQ - 1);
    const float4 w = *(const float4*)(cw + 4 * d);
    const float* p = xz + (long)m * (2 * DI) + d;
    float s = cb[d];
    s += (t >= 3 ? p[-3 * 2 * DI] : 0.f) * w.x;
    s += (t >= 2 ? p[-2 * 2 * DI] : 0.f) * w.y;
    s += (t >= 1 ? p[-1 * 2 * DI] : 0.f) * w.z;
    s += p[0] * w.w;
    xcbf[(long)m * DI + d] = f2bf(silu_f(s));
}

// xdbl[4096][128] -> softplus(col0)=dlt, cols 1..32 -> BC
__global__ __launch_bounds__(256) void xdbl_reduce_kernel(const float* __restrict__ xdbl,
                                                          float* __restrict__ dlt,
                                                          float* __restrict__ BC) {
    int idx = blockIdx.x * 256 + threadIdx.x;     // BL * 33
    if (idx >= BL * 33) return;
    int m = idx / 33;
    int j = idx - m * 33;
    float v = xdbl[(long)m * 128 + j];
    if (j == 0) dlt[m] = (v > 20.f) ? v : log1pf(expf(v));
    else        BC[(long)m * 32 + (j - 1)] = v;
}

// ---------------- selective scan, chunked-parallel ----------------
// Block = chunk c x 256-channel group. BC/delta staged in LDS (broadcast reads);
// all per-state values in f32x16 registers (constant indices only).

__global__ __launch_bounds__(256) void scan_pass1(const float* __restrict__ dlt,
                                                  const float* __restrict__ BC,
                                                  const unsigned short* __restrict__ xcbf,
                                                  const float* __restrict__ A_log,
                                                  float* __restrict__ P_,
                                                  float* __restrict__ S_) {
    __shared__ float sdl[CHK];
    __shared__ float sbc[CHK * 32];

    const int tid = threadIdx.x;
    const int c   = blockIdx.x;
    const int ch  = blockIdx.y * 256 + tid;
    const int b   = ch >> 11;
    const int d   = ch & (DI - 1);
    const long m0 = (long)b * LSEQ + (long)c * CHK;

    *(float4*)(sbc + tid * 4) = *(const float4*)(BC + m0 * 32 + tid * 4);
    if (tid < CHK) sdl[tid] = dlt[m0 + tid];

    f32x16 A, h, P;
#pragma unroll
    for (int s = 0; s < 16; ++s) {
        A[s] = -__expf(A_log[d * 16 + s]);
        h[s] = 0.f;
        P[s] = 1.f;
    }
    const unsigned short* ur = xcbf + m0 * DI + d;
    __syncthreads();

    for (int t = 0; t < CHK; ++t) {
        float dl = sdl[t];
        float u  = bf2f(ur[(long)t * DI]);
        float du = dl * u;
#pragma unroll
        for (int q = 0; q < 4; ++q) {
            f32x4 bq = *(const f32x4*)(sbc + t * 32 + q * 4);
#pragma unroll
            for (int j = 0; j < 4; ++j) {
                const int s = q * 4 + j;
                float dA = __expf(dl * A[s]);
                P[s] *= dA;
                h[s] = fmaf(dA, h[s], du * bq[j]);
            }
        }
    }
    float* pp = P_ + ((long)c * 4096 + ch) * 16;
    float* sp = S_ + ((long)c * 4096 + ch) * 16;
#pragma unroll
    for (int q = 0; q < 4; ++q) {
        *(f32x4*)(pp + q * 4) = (f32x4){P[q*4], P[q*4+1], P[q*4+2], P[q*4+3]};
        *(f32x4*)(sp + q * 4) = (f32x4){h[q*4], h[q*4+1], h[q*4+2], h[q*4+3]};
    }
}

// sequential combine over chunks; batched prefetch of 8 to hide latency.
__global__ __launch_bounds__(256) void scan_pass2(const float* __restrict__ P_,
                                                  float* __restrict__ S_) {
    const long idx = (long)blockIdx.x * 256 + threadIdx.x;  // (ch*16+s), 0..65535
    float h = 0.f;
    for (int c0 = 0; c0 < NC; c0 += 8) {
        float p[8], s[8];
#pragma unroll
        for (int i = 0; i < 8; ++i) {
            p[i] = P_[(long)(c0 + i) * 65536 + idx];
            s[i] = S_[(long)(c0 + i) * 65536 + idx];
        }
#pragma unroll
        for (int i = 0; i < 8; ++i) {
            S_[(long)(c0 + i) * 65536 + idx] = h;   // h0 entering chunk c0+i
            h = fmaf(p[i], h, s[i]);
        }
    }
}

__global__ __launch_bounds__(256) void scan_pass3(const float* __restrict__ dlt,
                                                  const float* __restrict__ BC,
                                                  const unsigned short* __restrict__ xcbf,
                                                  const float* __restrict__ xz,
                                                  const float* __restrict__ A_log,
                                                  const float* __restrict__ H0,
                                                  unsigned short* __restrict__ ybf) {
    __shared__ float sdl[CHK];
    __shared__ float sbc[CHK * 32];

    const int tid = threadIdx.x;
    const int c   = blockIdx.x;
    const int ch  = blockIdx.y * 256 + tid;
    const int b   = ch >> 11;
    const int d   = ch & (DI - 1);
    const long m0 = (long)b * LSEQ + (long)c * CHK;

    *(float4*)(sbc + tid * 4) = *(const float4*)(BC + m0 * 32 + tid * 4);
    if (tid < CHK) sdl[tid] = dlt[m0 + tid];

    f32x16 A, h;
    const float* h0p = H0 + ((long)c * 4096 + ch) * 16;
    {
        f32x4 h0a = *(const f32x4*)(h0p + 0);
        f32x4 h0b = *(const f32x4*)(h0p + 4);
        f32x4 h0c = *(const f32x4*)(h0p + 8);
        f32x4 h0d = *(const f32x4*)(h0p + 12);
#pragma unroll
        for (int j = 0; j < 4; ++j) {
            h[j]      = h0a[j];
            h[4 + j]  = h0b[j];
            h[8 + j]  = h0c[j];
            h[12 + j] = h0d[j];
        }
    }
#pragma unroll
    for (int s = 0; s < 16; ++s) A[s] = -__expf(A_log[d * 16 + s]);

    const unsigned short* ur = xcbf + m0 * DI + d;
    const float* zr = xz + m0 * (2 * DI) + DI + d;
    unsigned short* yr = ybf + m0 * DI + d;
    __syncthreads();

    for (int t = 0; t < CHK; ++t) {
        float dl = sdl[t];
        float u  = bf2f(ur[(long)t * DI]);
        float z  = zr[(long)t * 2 * DI];
        float du = dl * u;
        float y = 0.f;
#pragma unroll
        for (int q = 0; q < 4; ++q) {
            f32x4 bq = *(const f32x4*)(sbc + t * 32 + q * 4);
            f32x4 cq = *(const f32x4*)(sbc + t * 32 + 16 + q * 4);
#pragma unroll
            for (int j = 0; j < 4; ++j) {
                const int s = q * 4 + j;
                float dA = __expf(dl * A[s]);
                h[s] = fmaf(dA, h[s], du * bq[j]);
                y = fmaf(h[s], cq[j], y);
            }
        }
        yr[(long)t * DI] = f2bf(y * silu_f(z));
    }
}

// ---------------- host launcher ----------------
extern "C" void kernel_launch(void* const* d_in, const int* in_sizes, int n_in,
                              void* d_out, int out_size, void* d_ws, size_t ws_size,
                              hipStream_t stream) {
    const float* x      = (const float*)d_in[0];   // [2,2048,1024]
    const float* W_in   = (const float*)d_in[1];   // [4096,1024]
    const float* conv_w = (const float*)d_in[2];   // [2048,1,4]
    const float* conv_b = (const float*)d_in[3];   // [2048]
    const float* A_log  = (const float*)d_in[4];   // [2048,16]
    const float* W_x    = (const float*)d_in[5];   // [33,2048]
    const float* W_out  = (const float*)d_in[6];   // [1024,2048]
    float* out = (float*)d_out;                    // [2,2048,1024]

    char* w = (char*)d_ws;
    unsigned short* xbf  = (unsigned short*)(w + 0);          //  8,388,608 B
    unsigned short* wbf  = (unsigned short*)(w + 8388608);    //  8,388,608 B
    float*          xz   = (float*)(w + 16777216);            // 67,108,864 B
    unsigned short* xcbf = (unsigned short*)(w + 83886080);   // 16,777,216 B
    float*          dlt  = (float*)(w + 100663296);           //     16,384 B
    float*          BC   = (float*)(w + 100679680);           //    524,288 B
    float*          P_   = (float*)(w + 101203968);           // 16,777,216 B
    float*          S_   = (float*)(w + 117981184);           // 16,777,216 B  (end 134,758,400)

    // regions reused after gemm1 (stream-ordered):
    unsigned short* wobf = xbf;                               // W_out bf16 (4.2 MB)
    float*          xdbl = (float*)(w + 8388608);             // [4096][128] f32 (2 MB, over wbf)
    unsigned short* wxbf = (unsigned short*)(w + 10485760);   // [128][2048] bf16 (0.5 MB, over wbf)
    unsigned short* ybf  = (unsigned short*)P_;               // y*silu(z) bf16 (over dead P_)

    // 1) converts
    cvt_bf16_kernel<<<dim3(16384), dim3(256), 0, stream>>>(x, xbf, BL * DM);
    cvt_bf16_kernel<<<dim3(16384), dim3(256), 0, stream>>>(W_in, wbf, 2 * DI * DM);
    // 2) xz = x @ W_in^T   (M=4096, N=4096, K=1024)
    gemm_bf16_nt<<<dim3(32, 32), dim3(256), 0, stream>>>(xbf, wbf, xz, BL, 2 * DI, DM);
    // 3) weight conversions into released regions
    cvt_bf16_kernel<<<dim3(8192), dim3(256), 0, stream>>>(W_out, wobf, DM * DI);
    wx_pad_kernel<<<dim3(1024), dim3(256), 0, stream>>>(W_x, wxbf);
    // 4) depthwise conv + SiLU -> bf16
    conv_silu_kernel<<<dim3((BL * DI) / 256), dim3(256), 0, stream>>>(xz, conv_w, conv_b, xcbf);
    // 5) xdbl = xc @ W_x^T via MFMA (N padded to 128), then softplus/split
    gemm_bf16_nt<<<dim3(1, 32), dim3(256), 0, stream>>>(xcbf, wxbf, xdbl, BL, 128, DI);
    xdbl_reduce_kernel<<<dim3(528), dim3(256), 0, stream>>>(xdbl, dlt, BC);
    // 6) chunked selective scan
    scan_pass1<<<dim3(NC, 16), dim3(256), 0, stream>>>(dlt, BC, xcbf, A_log, P_, S_);
    scan_pass2<<<dim3(256), dim3(256), 0, stream>>>(P_, S_);
    scan_pass3<<<dim3(NC, 16), dim3(256), 0, stream>>>(dlt, BC, xcbf, xz, A_log, S_, ybf);
    // 7) out = y @ W_out^T   (M=4096, N=1024, K=2048)
    gemm_bf16_nt<<<dim3(8, 32), dim3(256), 0, stream>>>(ybf, wobf, out, BL, DM, DI);
}